// Round 11
// baseline (251.108 us; speedup 1.0000x reference)
//
#include <hip/hip_runtime.h>

#define NPIX 9216
#define IMH 96
#define IMW 96
#define NC 21
#define NCH 22          // 21 classes + norm channel
#define CP 24           // pixel-major channel pad; also M row pad
#define NMON 126        // monomials of degree <=4 in 5 vars
#define RAD 15
#define NITER 5
#define MG 11           // monomials per stage1 block
#define NMG 12          // ceil(126/11)
#define LDSS 260        // stage1 LDS pitch (float4-aligned, bank-spread)
#define MSZ 3024        // one M copy: 126 x 24
#define MCPY 8          // atomic-spread copies
#define MBUF (MCPY * MSZ)

// spatial taps exp(-d^2/18), sigma=3
__constant__ float GW[16] = {
    1.0f, 0.945959f, 0.800737f, 0.606531f, 0.411112f, 0.249352f,
    0.135335f, 0.0657285f, 0.0285655f, 0.0111090f, 0.00386592f,
    0.00120386f, 0.000335463f, 8.36523e-05f, 1.86640e-05f, 3.72665e-06f};

// near-minimax deg-4 poly for exp(t) on [0, 1.0384] (all coeffs > 0)
__constant__ float d_bk[5] = {1.000000f, 0.998959f, 0.509936f, 0.139441f, 0.070024f};

// ---- P: two block roles, one dispatch (round-7, proven; zeroes 3 M buffers) ----
__global__ __launch_bounds__(256) void prep_kernel(
    const float* __restrict__ img, const float* __restrict__ net_w,
    const float* __restrict__ net_b,
    float* __restrict__ u_pm, float* __restrict__ s_pm, float* __restrict__ s_cm,
    float* __restrict__ phi, float* __restrict__ Mall)
{
    __shared__ float wsh[567], bsh[21];
    __shared__ float sg_sh[NMON];
    const int tid = threadIdx.x;
    const int bid = blockIdx.x;

    if (bid < 36) {
        for (int i2 = tid; i2 < 567; i2 += 256) wsh[i2] = net_w[i2];
        if (tid < 21) bsh[tid] = net_b[tid];
        __syncthreads();

        const int px = bid * 256 + tid;
        const int i = px / IMW, j = px % IMW;
        for (int idx = px; idx < 3 * MBUF; idx += NPIX) Mall[idx] = 0.f;

        float acc[NC];
        #pragma unroll
        for (int o = 0; o < NC; o++) acc[o] = bsh[o];
        for (int ci = 0; ci < 3; ci++)
            for (int ky = 0; ky < 3; ky++)
                for (int kx = 0; kx < 3; kx++) {
                    const int ii = i + ky - 1, jj = j + kx - 1;
                    float v = 0.f;
                    if (ii >= 0 && ii < IMH && jj >= 0 && jj < IMW)
                        v = img[(ci * IMH + ii) * IMW + jj];
                    #pragma unroll
                    for (int o = 0; o < NC; o++)
                        acc[o] = fmaf(v, wsh[(ci * 3 + ky) * 3 + kx + o * 27], acc[o]);
                }
        {
            float4* up = (float4*)(u_pm + (size_t)px * CP);
            up[0] = make_float4(acc[0], acc[1], acc[2], acc[3]);
            up[1] = make_float4(acc[4], acc[5], acc[6], acc[7]);
            up[2] = make_float4(acc[8], acc[9], acc[10], acc[11]);
            up[3] = make_float4(acc[12], acc[13], acc[14], acc[15]);
            up[4] = make_float4(acc[16], acc[17], acc[18], acc[19]);
            up[5] = make_float4(acc[20], 0.f, 0.f, 0.f);
        }
        float mx = acc[0];
        #pragma unroll
        for (int o = 1; o < NC; o++) mx = fmaxf(mx, acc[o]);
        float sum = 0.f;
        #pragma unroll
        for (int o = 0; o < NC; o++) { acc[o] = __expf(acc[o] - mx); sum += acc[o]; }
        const float inv = 1.f / sum;
        #pragma unroll
        for (int o = 0; o < NC; o++) acc[o] *= inv;
        {
            float4* sp = (float4*)(s_pm + (size_t)px * CP);
            sp[0] = make_float4(acc[0], acc[1], acc[2], acc[3]);
            sp[1] = make_float4(acc[4], acc[5], acc[6], acc[7]);
            sp[2] = make_float4(acc[8], acc[9], acc[10], acc[11]);
            sp[3] = make_float4(acc[12], acc[13], acc[14], acc[15]);
            sp[4] = make_float4(acc[16], acc[17], acc[18], acc[19]);
            sp[5] = make_float4(acc[20], 1.f, 0.f, 0.f);
        }
        #pragma unroll
        for (int o = 0; o < NC; o++) s_cm[(size_t)o * NPIX + px] = acc[o];
        s_cm[(size_t)21 * NPIX + px] = 1.f;
    } else {
        for (int m = tid; m < NMON; m += 256) {
            int e1 = 0, e2 = 0, e3 = 0, e4 = 0, e5 = 0, cnt = 0;
            bool done = false;
            for (int a = 0; a <= 4 && !done; a++)
                for (int b2 = 0; b2 <= 4 - a && !done; b2++)
                    for (int c = 0; c <= 4 - a - b2 && !done; c++)
                        for (int d = 0; d <= 4 - a - b2 - c && !done; d++) {
                            const int rem = 4 - a - b2 - c - d;
                            if (m - cnt <= rem) {
                                e1 = a; e2 = b2; e3 = c; e4 = d; e5 = m - cnt;
                                done = true;
                            } else cnt += rem + 1;
                        }
            const float fact[5] = {1.f, 1.f, 2.f, 6.f, 24.f};
            const int k = e1 + e2 + e3 + e4 + e5;
            sg_sh[m] = sqrtf(d_bk[k] * fact[k] /
                             (fact[e1] * fact[e2] * fact[e3] * fact[e4] * fact[e5]));
        }
        __syncthreads();

        const int px = (bid - 36) * 32 + (tid & 31);
        const unsigned c0 = (tid >> 5) * 16;
        const int i = px / IMW, j = px % IMW;
        const float fv[5] = {(float)j * (1.0f / 160.0f), (float)i * (1.0f / 160.0f),
                             img[0 * NPIX + px] * (1.0f / 3.0f),
                             img[1 * NPIX + px] * (1.0f / 3.0f),
                             img[2 * NPIX + px] * (1.0f / 3.0f)};
        const float env = __expf(-0.5f * (fv[0]*fv[0] + fv[1]*fv[1] + fv[2]*fv[2] +
                                          fv[3]*fv[3] + fv[4]*fv[4]));
        int m = 0;
        float p1 = env;
        #pragma unroll
        for (int e1 = 0; e1 <= 4; e1++) {
            float p2 = p1;
            #pragma unroll
            for (int e2 = 0; e2 <= 4 - e1; e2++) {
                float p3 = p2;
                #pragma unroll
                for (int e3 = 0; e3 <= 4 - e1 - e2; e3++) {
                    float p4 = p3;
                    #pragma unroll
                    for (int e4 = 0; e4 <= 4 - e1 - e2 - e3; e4++) {
                        float p5 = p4;
                        #pragma unroll
                        for (int e5 = 0; e5 <= 4 - e1 - e2 - e3 - e4; e5++) {
                            if ((unsigned)(m - c0) < 16u)
                                phi[(size_t)m * NPIX + px] = sg_sh[m] * p5;
                            ++m;
                            p5 *= fv[4];
                        }
                        p4 *= fv[3];
                    }
                    p3 *= fv[2];
                }
                p2 *= fv[1];
            }
            p1 *= fv[0];
        }
    }
}

// ---- K1 (bootstrap): stage1 GEMM -> M buffer 0 (8-copy) || conv-x of s0 ----
__global__ __launch_bounds__(256) void k1_kernel(
    const float* __restrict__ s_pm, const float* __restrict__ s_cm,
    const float* __restrict__ phi, float* __restrict__ sx, float* __restrict__ M0)
{
    __shared__ float smem[(NCH + MG) * LDSS];
    const int bid = blockIdx.x, tid = threadIdx.x;
    if (bid < NMG * 36) {
        const int g = bid / 36, chunk = bid % 36;
        const int m0 = g * MG;
        const int mcnt = (NMON - m0 < MG) ? (NMON - m0) : MG;
        float* s_sh = smem;
        float* p_sh = smem + NCH * LDSS;
        {
            const float4* sp = (const float4*)(s_pm + (size_t)(chunk * 256 + tid) * CP);
            #pragma unroll
            for (int v = 0; v < 6; v++) {
                const float4 t = sp[v];
                const int c = 4 * v;
                if (c < NCH)     s_sh[c * LDSS + tid] = t.x;
                if (c + 1 < NCH) s_sh[(c + 1) * LDSS + tid] = t.y;
                if (c + 2 < NCH) s_sh[(c + 2) * LDSS + tid] = t.z;
                if (c + 3 < NCH) s_sh[(c + 3) * LDSS + tid] = t.w;
            }
        }
        for (int idx = tid; idx < mcnt * 64; idx += 256) {
            const int mm = idx >> 6, p4 = idx & 63;
            const float4 t = *(const float4*)(phi + (size_t)(m0 + mm) * NPIX +
                                              chunk * 256 + p4 * 4);
            *(float4*)(p_sh + mm * LDSS + p4 * 4) = t;
        }
        __syncthreads();
        const int c = tid % NCH, msub = tid / NCH;
        if (msub < mcnt) {
            const float* sr = s_sh + c * LDSS;
            const float* pr = p_sh + msub * LDSS;
            float acc = 0.f;
            for (int p4 = 0; p4 < 64; p4++) {
                const float4 sv = *(const float4*)(sr + p4 * 4);
                const float4 pv = *(const float4*)(pr + p4 * 4);
                acc += pv.x * sv.x + pv.y * sv.y + pv.z * sv.z + pv.w * sv.w;
            }
            atomicAdd(&M0[(bid & 7) * MSZ + (m0 + msub) * CP + c], acc);
        }
    } else {
        const int u2 = bid - NMG * 36;
        const int ch = u2 / 36, pc = u2 % 36;
        const int n = pc * 256 + tid, j = n % IMW;
        const float* row = s_cm + (size_t)ch * NPIX + (n - j);
        float a = GW[0] * row[j];
        #pragma unroll
        for (int d = 1; d <= RAD; d++) {
            const float l = (j - d >= 0) ? row[j - d] : 0.f;
            const float r = (j + d < IMW) ? row[j + d] : 0.f;
            a = fmaf(GW[d], l + r, a);
        }
        sx[(size_t)ch * NPIX + n] = a;
    }
}

// ---- KAB: one full iteration per dispatch. Block = one image row (96 blocks,
//      1024 threads). Head: conv-y + stage2 + combine + softmax. Tail:
//      row-local conv-x -> sxout, M(it+1) partial GEMM (8-copy atomics). ----
__global__ __launch_bounds__(1024) void kab_kernel(
    const float* __restrict__ sxin, float* __restrict__ sxout,
    const float* __restrict__ phi,
    const float* __restrict__ Mcur, float* __restrict__ Mnext,
    float* __restrict__ Mzero,
    const float* __restrict__ u_pm, float* __restrict__ s_pm,
    const float* __restrict__ sp_w, const float* __restrict__ sp_b,
    const float* __restrict__ bl_w, const float* __restrict__ bl_b,
    const float* __restrict__ comp_w, const float* __restrict__ comp_b,
    float* __restrict__ out, int last)
{
    __shared__ float Msh[MSZ];            // [126][24] 12.1 KB
    __shared__ float cy_sh[96 * 25];      // conv-y (+norm)
    __shared__ float blv_sh[96 * 25];     // stage2 (+pads)
    __shared__ float mp_sh[96 * CP];
    __shared__ float q_sh[96 * CP];       // u -> logits
    __shared__ float srow_sh[96 * 25];    // fresh probs (+norm)
    __shared__ float wsh[1386 + 63];
    const int tid = threadIdx.x;
    const int i0 = blockIdx.x;            // row [0,96)
    const int px0 = i0 * IMW;

    // preamble: M = sum of 8 copies (float4), weights, zero it+2 buffer, u
    if (tid < MSZ / 4) {
        const float4* Mc4 = (const float4*)Mcur;
        float4 v = Mc4[tid];
        #pragma unroll
        for (int k = 1; k < MCPY; k++) {
            const float4 t = Mc4[k * (MSZ / 4) + tid];
            v.x += t.x; v.y += t.y; v.z += t.z; v.w += t.w;
        }
        ((float4*)Msh)[tid] = v;
    }
    for (int idx = tid; idx < 441; idx += 1024) {
        wsh[idx] = sp_w[idx]; wsh[441 + idx] = bl_w[idx]; wsh[882 + idx] = comp_w[idx];
    }
    if (tid < 21) {
        wsh[1323 + tid] = sp_b[tid]; wsh[1344 + tid] = bl_b[tid];
        wsh[1365 + tid] = comp_b[tid];
    }
    if (!last && tid < MBUF / 96)          // 252 floats per block
        Mzero[i0 * (MBUF / 96) + tid] = 0.f;
    for (int idx = tid; idx < 96 * CP; idx += 1024)
        q_sh[idx] = u_pm[(size_t)px0 * CP + idx];

    // conv-y from sxin (global, prev dispatch)
    for (int task = tid; task < NCH * 96; task += 1024) {
        const int ch = task / 96, p = task - (task / 96) * 96;
        const float* plane = sxin + (size_t)ch * NPIX;
        const int n = px0 + p;
        float a = GW[0] * plane[n];
        #pragma unroll
        for (int d = 1; d <= RAD; d++) {
            const float t = (i0 - d >= 0) ? plane[n - d * IMW] : 0.f;
            const float b = (i0 + d < IMH) ? plane[n + d * IMW] : 0.f;
            a = fmaf(GW[d], t + b, a);
        }
        cy_sh[p * 25 + ch] = a;
    }
    __syncthreads();

    // stage2: task = (p, c-quad); phi row-coalesced from global, M float4 LDS
    if (tid < 96 * 6) {
        const int p = tid / 6, cq = tid - (tid / 6) * 6;
        const int c0 = cq * 4;
        float4 a = make_float4(0.f, 0.f, 0.f, 0.f);
        const float* pcol = phi + px0 + p;
        const float4* M4 = (const float4*)Msh;
        for (int mm = 0; mm < NMON; mm++) {
            const float ph = pcol[(size_t)mm * NPIX];
            const float4 Mv = M4[mm * 6 + cq];
            a.x = fmaf(ph, Mv.x, a.x); a.y = fmaf(ph, Mv.y, a.y);
            a.z = fmaf(ph, Mv.z, a.z); a.w = fmaf(ph, Mv.w, a.w);
        }
        blv_sh[p * 25 + c0]     = a.x;
        blv_sh[p * 25 + c0 + 1] = a.y;
        blv_sh[p * 25 + c0 + 2] = a.z;   // c0=20: slots 22,23 are pads
        blv_sh[p * 25 + c0 + 3] = a.w;
    }
    __syncthreads();

    // matmul1: 2016 tasks, strided (FIX: was if-guarded, lost tasks >= 1024)
    for (int t = tid; t < 96 * NC; t += 1024) {
        const int o = t / 96, p = t - (t / 96) * 96;
        const float* cyr = cy_sh + p * 25;
        const float* blr = blv_sh + p * 25;
        float dS = 0.f, dB = 0.f;
        #pragma unroll
        for (int c = 0; c < NC; c++) {
            dS = fmaf(wsh[o * NC + c], cyr[c], dS);
            dB = fmaf(wsh[441 + o * NC + c], blr[c], dB);
        }
        mp_sh[p * CP + o] = wsh[1323 + o] + wsh[1344 + o] +
                            dS / cyr[21] + dB / blr[21];
    }
    __syncthreads();

    // matmul2: 2016 tasks, strided (FIX: same)
    for (int t = tid; t < 96 * NC; t += 1024) {
        const int o = t / 96, p = t - (t / 96) * 96;
        const float* mpr = mp_sh + p * CP;
        float d = wsh[1365 + o];
        #pragma unroll
        for (int c = 0; c < NC; c++) d = fmaf(wsh[882 + o * NC + c], mpr[c], d);
        q_sh[p * CP + o] = q_sh[p * CP + o] - d;
    }
    __syncthreads();

    // softmax; probs -> srow_sh (25-pitch) + s_pm (global, for tail L1 reads)
    if (tid < 96) {
        const int p = tid;
        float q[NC];
        #pragma unroll
        for (int o = 0; o < NC; o++) q[o] = q_sh[p * CP + o];
        float mx = q[0];
        #pragma unroll
        for (int o = 1; o < NC; o++) mx = fmaxf(mx, q[o]);
        float sum = 0.f;
        #pragma unroll
        for (int o = 0; o < NC; o++) { q[o] = __expf(q[o] - mx); sum += q[o]; }
        const float inv = 1.f / sum;
        #pragma unroll
        for (int o = 0; o < NC; o++) q[o] *= inv;
        #pragma unroll
        for (int o = 0; o < NC; o++) srow_sh[p * 25 + o] = q[o];
        srow_sh[p * 25 + 21] = 1.f;
        if (last) {
            #pragma unroll
            for (int o = 0; o < NC; o++) out[(size_t)o * NPIX + px0 + p] = q[o];
        } else {
            float4* sp = (float4*)(s_pm + (size_t)(px0 + p) * CP);
            sp[0] = make_float4(q[0], q[1], q[2], q[3]);
            sp[1] = make_float4(q[4], q[5], q[6], q[7]);
            sp[2] = make_float4(q[8], q[9], q[10], q[11]);
            sp[3] = make_float4(q[12], q[13], q[14], q[15]);
            sp[4] = make_float4(q[16], q[17], q[18], q[19]);
            sp[5] = make_float4(q[20], 1.f, 0.f, 0.f);
        }
    }
    __syncthreads();
    if (last) return;

    // tail a: row-local conv-x -> sxout (next conv-y input)
    for (int task = tid; task < NCH * 96; task += 1024) {
        const int ch = task / 96, p = task - (task / 96) * 96;
        float a = GW[0] * srow_sh[p * 25 + ch];
        #pragma unroll
        for (int d = 1; d <= RAD; d++) {
            const float l = (p - d >= 0) ? srow_sh[(p - d) * 25 + ch] : 0.f;
            const float r = (p + d < 96) ? srow_sh[(p + d) * 25 + ch] : 0.f;
            a = fmaf(GW[d], l + r, a);
        }
        sxout[(size_t)ch * NPIX + px0 + p] = a;
    }

    // tail b: M(it+1) partial: task = (m, c-quad); phi rows + s_pm via L1
    if (tid < NMON * 6) {
        const int m = tid / 6, cq = tid - (tid / 6) * 6;
        const int c0 = cq * 4;
        const float* prow = phi + (size_t)m * NPIX + px0;
        const float4* s4 = (const float4*)(s_pm + (size_t)px0 * CP);
        float4 a = make_float4(0.f, 0.f, 0.f, 0.f);
        for (int p = 0; p < 96; p++) {
            const float ph = prow[p];
            const float4 sv = s4[p * 6 + cq];
            a.x = fmaf(ph, sv.x, a.x); a.y = fmaf(ph, sv.y, a.y);
            a.z = fmaf(ph, sv.z, a.z); a.w = fmaf(ph, sv.w, a.w);
        }
        float* Md = Mnext + (i0 & 7) * MSZ + m * CP + c0;
        atomicAdd(Md, a.x);
        atomicAdd(Md + 1, a.y);
        if (cq < 5) {                      // skip pad cols 22,23
            atomicAdd(Md + 2, a.z);
            atomicAdd(Md + 3, a.w);
        }
    }
}

extern "C" void kernel_launch(void* const* d_in, const int* in_sizes, int n_in,
                              void* d_out, int out_size, void* d_ws, size_t ws_size,
                              hipStream_t stream) {
    const float* img    = (const float*)d_in[0];
    const float* net_w  = (const float*)d_in[1];
    const float* net_b  = (const float*)d_in[2];
    const float* sp_w   = (const float*)d_in[3];
    const float* sp_b   = (const float*)d_in[4];
    const float* bl_w   = (const float*)d_in[5];
    const float* bl_b   = (const float*)d_in[6];
    const float* comp_w = (const float*)d_in[7];
    const float* comp_b = (const float*)d_in[8];

    float* u_pm = (float*)d_ws;                  // [NPIX][24]
    float* s_pm = u_pm + (size_t)NPIX * CP;      // [NPIX][24] (probs scratch)
    float* s_cm = s_pm + (size_t)NPIX * CP;      // [22][NPIX] (prep only)
    float* sx0  = s_cm + (size_t)NCH * NPIX;     // [22][NPIX] double-buffered
    float* sx1  = sx0 + (size_t)NCH * NPIX;
    float* phi  = sx1 + (size_t)NCH * NPIX;      // [126][NPIX]
    float* M3   = phi + (size_t)NMON * NPIX;     // [3][8][3024]

    float* out = (float*)d_out;

    prep_kernel<<<dim3(36 + 288), dim3(256), 0, stream>>>(
        img, net_w, net_b, u_pm, s_pm, s_cm, phi, M3);
    k1_kernel<<<dim3(NMG * 36 + NCH * 36), dim3(256), 0, stream>>>(
        s_pm, s_cm, phi, sx0, M3);               // M buffer 0 + sx(it0)
    for (int it = 0; it < NITER; it++) {
        float* Mc = M3 + (size_t)(it % 3) * MBUF;
        float* Mn = M3 + (size_t)((it + 1) % 3) * MBUF;
        float* Mz = M3 + (size_t)((it + 2) % 3) * MBUF;
        float* sin  = (it & 1) ? sx1 : sx0;
        float* sout = (it & 1) ? sx0 : sx1;
        kab_kernel<<<dim3(96), dim3(1024), 0, stream>>>(
            sin, sout, phi, Mc, Mn, Mz, u_pm, s_pm,
            sp_w, sp_b, bl_w, bl_b, comp_w, comp_b,
            out, it == NITER - 1 ? 1 : 0);
    }
}

// Round 12
// 204.196 us; speedup vs baseline: 1.2297x; 1.2297x over previous
//
#include <hip/hip_runtime.h>

#define NPIX 9216
#define IMH 96
#define IMW 96
#define NC 21
#define NCH 22          // 21 classes + norm channel
#define CP 24           // pixel-major channel pad; also M row pad
#define NMON 126        // monomials of degree <=4 in 5 vars
#define RAD 15
#define NITER 5
#define MG 11           // monomials per stage1 block
#define NMG 12          // ceil(126/11)
#define LDSS 260        // stage1 LDS pitch (float4-aligned, bank-spread)
#define MPAD 3072       // M buffer stride (>=126*24, float4-aligned)
#define K2PX 8          // k2 pixels per block (1152 blocks = 4.5/CU)

// spatial taps exp(-d^2/18), sigma=3
__constant__ float GW[16] = {
    1.0f, 0.945959f, 0.800737f, 0.606531f, 0.411112f, 0.249352f,
    0.135335f, 0.0657285f, 0.0285655f, 0.0111090f, 0.00386592f,
    0.00120386f, 0.000335463f, 8.36523e-05f, 1.86640e-05f, 3.72665e-06f};

// near-minimax deg-4 poly for exp(t) on [0, 1.0384] (all coeffs > 0)
__constant__ float d_bk[5] = {1.000000f, 0.998959f, 0.509936f, 0.139441f, 0.070024f};

// ---- P: two block roles, one dispatch (round-7, proven) ----
__global__ __launch_bounds__(256) void prep_kernel(
    const float* __restrict__ img, const float* __restrict__ net_w,
    const float* __restrict__ net_b,
    float* __restrict__ u_pm, float* __restrict__ s_pm, float* __restrict__ s_cm,
    float* __restrict__ phi, float* __restrict__ M0)
{
    __shared__ float wsh[567], bsh[21];
    __shared__ float sg_sh[NMON];
    const int tid = threadIdx.x;
    const int bid = blockIdx.x;

    if (bid < 36) {
        // ---- role A: unary conv + softmax + u/s + zero M0 ----
        for (int i2 = tid; i2 < 567; i2 += 256) wsh[i2] = net_w[i2];
        if (tid < 21) bsh[tid] = net_b[tid];
        __syncthreads();

        const int px = bid * 256 + tid;
        const int i = px / IMW, j = px % IMW;
        if (px < MPAD) M0[px] = 0.f;      // zero padded M buffer 0

        float acc[NC];
        #pragma unroll
        for (int o = 0; o < NC; o++) acc[o] = bsh[o];
        for (int ci = 0; ci < 3; ci++)
            for (int ky = 0; ky < 3; ky++)
                for (int kx = 0; kx < 3; kx++) {
                    const int ii = i + ky - 1, jj = j + kx - 1;
                    float v = 0.f;
                    if (ii >= 0 && ii < IMH && jj >= 0 && jj < IMW)
                        v = img[(ci * IMH + ii) * IMW + jj];
                    #pragma unroll
                    for (int o = 0; o < NC; o++)
                        acc[o] = fmaf(v, wsh[(ci * 3 + ky) * 3 + kx + o * 27], acc[o]);
                }
        {   // u then softmax
            float4* up = (float4*)(u_pm + (size_t)px * CP);
            up[0] = make_float4(acc[0], acc[1], acc[2], acc[3]);
            up[1] = make_float4(acc[4], acc[5], acc[6], acc[7]);
            up[2] = make_float4(acc[8], acc[9], acc[10], acc[11]);
            up[3] = make_float4(acc[12], acc[13], acc[14], acc[15]);
            up[4] = make_float4(acc[16], acc[17], acc[18], acc[19]);
            up[5] = make_float4(acc[20], 0.f, 0.f, 0.f);
        }
        float mx = acc[0];
        #pragma unroll
        for (int o = 1; o < NC; o++) mx = fmaxf(mx, acc[o]);
        float sum = 0.f;
        #pragma unroll
        for (int o = 0; o < NC; o++) { acc[o] = __expf(acc[o] - mx); sum += acc[o]; }
        const float inv = 1.f / sum;
        #pragma unroll
        for (int o = 0; o < NC; o++) acc[o] *= inv;
        {
            float4* sp = (float4*)(s_pm + (size_t)px * CP);
            sp[0] = make_float4(acc[0], acc[1], acc[2], acc[3]);
            sp[1] = make_float4(acc[4], acc[5], acc[6], acc[7]);
            sp[2] = make_float4(acc[8], acc[9], acc[10], acc[11]);
            sp[3] = make_float4(acc[12], acc[13], acc[14], acc[15]);
            sp[4] = make_float4(acc[16], acc[17], acc[18], acc[19]);
            sp[5] = make_float4(acc[20], 1.f, 0.f, 0.f);
        }
        #pragma unroll
        for (int o = 0; o < NC; o++) s_cm[(size_t)o * NPIX + px] = acc[o];
        s_cm[(size_t)21 * NPIX + px] = 1.f;
    } else {
        // ---- role B: phi, 8 threads/pixel, 16-monomial store window each ----
        for (int m = tid; m < NMON; m += 256) {
            int e1 = 0, e2 = 0, e3 = 0, e4 = 0, e5 = 0, cnt = 0;
            bool done = false;
            for (int a = 0; a <= 4 && !done; a++)
                for (int b2 = 0; b2 <= 4 - a && !done; b2++)
                    for (int c = 0; c <= 4 - a - b2 && !done; c++)
                        for (int d = 0; d <= 4 - a - b2 - c && !done; d++) {
                            const int rem = 4 - a - b2 - c - d;
                            if (m - cnt <= rem) {
                                e1 = a; e2 = b2; e3 = c; e4 = d; e5 = m - cnt;
                                done = true;
                            } else cnt += rem + 1;
                        }
            const float fact[5] = {1.f, 1.f, 2.f, 6.f, 24.f};
            const int k = e1 + e2 + e3 + e4 + e5;
            sg_sh[m] = sqrtf(d_bk[k] * fact[k] /
                             (fact[e1] * fact[e2] * fact[e3] * fact[e4] * fact[e5]));
        }
        __syncthreads();

        const int px = (bid - 36) * 32 + (tid & 31);
        const unsigned c0 = (tid >> 5) * 16;      // this thread's store window
        const int i = px / IMW, j = px % IMW;
        const float fv[5] = {(float)j * (1.0f / 160.0f), (float)i * (1.0f / 160.0f),
                             img[0 * NPIX + px] * (1.0f / 3.0f),
                             img[1 * NPIX + px] * (1.0f / 3.0f),
                             img[2 * NPIX + px] * (1.0f / 3.0f)};
        const float env = __expf(-0.5f * (fv[0]*fv[0] + fv[1]*fv[1] + fv[2]*fv[2] +
                                          fv[3]*fv[3] + fv[4]*fv[4]));
        int m = 0;
        float p1 = env;
        #pragma unroll
        for (int e1 = 0; e1 <= 4; e1++) {
            float p2 = p1;
            #pragma unroll
            for (int e2 = 0; e2 <= 4 - e1; e2++) {
                float p3 = p2;
                #pragma unroll
                for (int e3 = 0; e3 <= 4 - e1 - e2; e3++) {
                    float p4 = p3;
                    #pragma unroll
                    for (int e4 = 0; e4 <= 4 - e1 - e2 - e3; e4++) {
                        float p5 = p4;
                        #pragma unroll
                        for (int e5 = 0; e5 <= 4 - e1 - e2 - e3 - e4; e5++) {
                            if ((unsigned)(m - c0) < 16u)
                                phi[(size_t)m * NPIX + px] = sg_sh[m] * p5;
                            ++m;
                            p5 *= fv[4];
                        }
                        p4 *= fv[3];
                    }
                    p3 *= fv[2];
                }
                p2 *= fv[1];
            }
            p1 *= fv[0];
        }
    }
}

// ---- K1: stage1 GEMM (LDS b128 dot, atomic M, CP-padded rows) || conv-x ----
__global__ __launch_bounds__(256) void k1_kernel(
    const float* __restrict__ s_pm, const float* __restrict__ s_cm,
    const float* __restrict__ phi, float* __restrict__ sx, float* __restrict__ M)
{
    __shared__ float smem[(NCH + MG) * LDSS];
    const int bid = blockIdx.x, tid = threadIdx.x;
    if (bid < NMG * 36) {
        const int g = bid / 36, chunk = bid % 36;
        const int m0 = g * MG;
        const int mcnt = (NMON - m0 < MG) ? (NMON - m0) : MG;
        float* s_sh = smem;
        float* p_sh = smem + NCH * LDSS;
        {
            const float4* sp = (const float4*)(s_pm + (size_t)(chunk * 256 + tid) * CP);
            #pragma unroll
            for (int v = 0; v < 6; v++) {
                const float4 t = sp[v];
                const int c = 4 * v;
                if (c < NCH)     s_sh[c * LDSS + tid] = t.x;
                if (c + 1 < NCH) s_sh[(c + 1) * LDSS + tid] = t.y;
                if (c + 2 < NCH) s_sh[(c + 2) * LDSS + tid] = t.z;
                if (c + 3 < NCH) s_sh[(c + 3) * LDSS + tid] = t.w;
            }
        }
        for (int idx = tid; idx < mcnt * 64; idx += 256) {
            const int mm = idx >> 6, p4 = idx & 63;
            const float4 t = *(const float4*)(phi + (size_t)(m0 + mm) * NPIX +
                                              chunk * 256 + p4 * 4);
            *(float4*)(p_sh + mm * LDSS + p4 * 4) = t;
        }
        __syncthreads();
        const int c = tid % NCH, msub = tid / NCH;
        if (msub < mcnt) {
            const float* sr = s_sh + c * LDSS;
            const float* pr = p_sh + msub * LDSS;
            float acc = 0.f;
            for (int p4 = 0; p4 < 64; p4++) {
                const float4 sv = *(const float4*)(sr + p4 * 4);
                const float4 pv = *(const float4*)(pr + p4 * 4);
                acc += pv.x * sv.x + pv.y * sv.y + pv.z * sv.z + pv.w * sv.w;
            }
            atomicAdd(&M[(m0 + msub) * CP + c], acc);
        }
    } else {
        const int u2 = bid - NMG * 36;        // [0, 792)
        const int ch = u2 / 36, pc = u2 % 36;
        const int n = pc * 256 + tid, j = n % IMW;
        const float* row = s_cm + (size_t)ch * NPIX + (n - j);
        float a = GW[0] * row[j];
        #pragma unroll
        for (int d = 1; d <= RAD; d++) {
            const float l = (j - d >= 0) ? row[j - d] : 0.f;
            const float r = (j + d < IMW) ? row[j + d] : 0.f;
            a = fmaf(GW[d], l + r, a);
        }
        sx[(size_t)ch * NPIX + n] = a;
    }
}

// ---- K2: conv-y + stage2 + combine + softmax. 8 px/block, 1152 blocks.
//      M read as float4 [126][24]; phi direct from global; u prefetched. ----
__global__ __launch_bounds__(256) void k2_kernel(
    const float* __restrict__ sx, const float* __restrict__ phi,
    const float* __restrict__ M, float* __restrict__ Mnext,
    const float* __restrict__ u_pm,
    const float* __restrict__ sp_w, const float* __restrict__ sp_b,
    const float* __restrict__ bl_w, const float* __restrict__ bl_b,
    const float* __restrict__ comp_w, const float* __restrict__ comp_b,
    float* __restrict__ s_pm, float* __restrict__ s_cm,
    float* __restrict__ out, int write_out)
{
    __shared__ float Msh[NMON * CP];       // 12.1 KB, [126][24]
    __shared__ float cy_sh[K2PX * 25];     // conv-y (+norm slot)
    __shared__ float blv_sh[K2PX * 25];    // stage2 result
    __shared__ float mp_sh[K2PX * CP];
    __shared__ float q_sh[K2PX * CP];      // u (prefetch) -> q
    __shared__ float wsh[1386 + 63];
    const int tid = threadIdx.x;
    const int px0 = blockIdx.x * K2PX;
    const int i0 = px0 / IMW;              // block-uniform row (8 | 96)

    // Msh: vectorized copy of padded M (pad cols are zero-initialized, unwritten)
    {
        float4* M4 = (float4*)Msh;
        const float4* Mc4 = (const float4*)M;
        for (int idx = tid; idx < NMON * CP / 4; idx += 256) M4[idx] = Mc4[idx];
    }
    for (int idx = tid; idx < 441; idx += 256) {
        wsh[idx] = sp_w[idx]; wsh[441 + idx] = bl_w[idx]; wsh[882 + idx] = comp_w[idx];
    }
    if (tid < 21) {
        wsh[1323 + tid] = sp_b[tid]; wsh[1344 + tid] = bl_b[tid];
        wsh[1365 + tid] = comp_b[tid];
    }
    if (blockIdx.x < 12) {
        const int idx = blockIdx.x * 256 + tid;
        if (idx < MPAD) Mnext[idx] = 0.f;
    }
    // u prefetch (contiguous 8*24 floats)
    for (int idx = tid; idx < K2PX * CP; idx += 256)
        q_sh[idx] = u_pm[(size_t)px0 * CP + idx];
    // conv-y: 22ch x 8px tasks (single round)
    if (tid < NCH * K2PX) {
        const int ch = tid >> 3, p = tid & 7;
        const int n = px0 + p;
        const float* plane = sx + (size_t)ch * NPIX;
        float a = GW[0] * plane[n];
        #pragma unroll
        for (int d = 1; d <= RAD; d++) {
            const float t = (i0 - d >= 0) ? plane[n - d * IMW] : 0.f;
            const float b = (i0 + d < IMH) ? plane[n + d * IMW] : 0.f;
            a = fmaf(GW[d], t + b, a);
        }
        cy_sh[p * 25 + ch] = a;
    }
    __syncthreads();

    // stage2: thread = (p = tid&7, ch = tid>>3); 1 channel each; phi from global
    {
        const int p = tid & 7, ch = tid >> 3;
        if (ch < NCH) {
            float a0 = 0.f;
            const float* pcol = phi + px0 + p;
            for (int mm = 0; mm < NMON; mm++)
                a0 = fmaf(pcol[(size_t)mm * NPIX], Msh[mm * CP + ch], a0);
            blv_sh[p * 25 + ch] = a0;
        }
    }
    __syncthreads();

    // matmul1: mp = sp_b + bl_b + (sp_w@cy)/cy_norm + (bl_w@blv)/blv_norm
    if (tid < K2PX * NC) {
        const int p = tid & 7, o = tid >> 3;
        const float* cyr = cy_sh + p * 25;
        const float* blr = blv_sh + p * 25;
        float dS = 0.f, dB = 0.f;
        #pragma unroll
        for (int c = 0; c < NC; c++) {
            dS = fmaf(wsh[o * NC + c], cyr[c], dS);
            dB = fmaf(wsh[441 + o * NC + c], blr[c], dB);
        }
        mp_sh[p * CP + o] = wsh[1323 + o] + wsh[1344 + o] +
                            dS / cyr[21] + dB / blr[21];
    }
    __syncthreads();

    // matmul2: q = u - (comp_w @ mp + comp_b)   (u already in q_sh)
    if (tid < K2PX * NC) {
        const int p = tid & 7, o = tid >> 3;
        const float* mpr = mp_sh + p * CP;
        float d = wsh[1365 + o];
        #pragma unroll
        for (int c = 0; c < NC; c++) d = fmaf(wsh[882 + o * NC + c], mpr[c], d);
        q_sh[p * CP + o] = q_sh[p * CP + o] - d;
    }
    __syncthreads();

    // softmax + writes, thread = pixel
    if (tid < K2PX) {
        const int n = px0 + tid;
        float q[NC];
        #pragma unroll
        for (int o = 0; o < NC; o++) q[o] = q_sh[tid * CP + o];
        float mx = q[0];
        #pragma unroll
        for (int o = 1; o < NC; o++) mx = fmaxf(mx, q[o]);
        float sum = 0.f;
        #pragma unroll
        for (int o = 0; o < NC; o++) { q[o] = __expf(q[o] - mx); sum += q[o]; }
        const float inv = 1.f / sum;
        #pragma unroll
        for (int o = 0; o < NC; o++) q[o] *= inv;

        float4* sp = (float4*)(s_pm + (size_t)n * CP);
        sp[0] = make_float4(q[0], q[1], q[2], q[3]);
        sp[1] = make_float4(q[4], q[5], q[6], q[7]);
        sp[2] = make_float4(q[8], q[9], q[10], q[11]);
        sp[3] = make_float4(q[12], q[13], q[14], q[15]);
        sp[4] = make_float4(q[16], q[17], q[18], q[19]);
        sp[5] = make_float4(q[20], 1.f, 0.f, 0.f);
        #pragma unroll
        for (int o = 0; o < NC; o++) s_cm[(size_t)o * NPIX + n] = q[o];
        s_cm[(size_t)21 * NPIX + n] = 1.f;
        if (write_out)
            #pragma unroll
            for (int o = 0; o < NC; o++) out[(size_t)o * NPIX + n] = q[o];
    }
}

extern "C" void kernel_launch(void* const* d_in, const int* in_sizes, int n_in,
                              void* d_out, int out_size, void* d_ws, size_t ws_size,
                              hipStream_t stream) {
    const float* img    = (const float*)d_in[0];
    const float* net_w  = (const float*)d_in[1];
    const float* net_b  = (const float*)d_in[2];
    const float* sp_w   = (const float*)d_in[3];
    const float* sp_b   = (const float*)d_in[4];
    const float* bl_w   = (const float*)d_in[5];
    const float* bl_b   = (const float*)d_in[6];
    const float* comp_w = (const float*)d_in[7];
    const float* comp_b = (const float*)d_in[8];

    float* u_pm = (float*)d_ws;                  // [NPIX][24]
    float* s_pm = u_pm + (size_t)NPIX * CP;      // [NPIX][24]
    float* s_cm = s_pm + (size_t)NPIX * CP;      // [22][NPIX]
    float* sx   = s_cm + (size_t)NCH * NPIX;     // [22][NPIX]
    float* phi  = sx + (size_t)NCH * NPIX;       // [126][NPIX]
    float* M    = phi + (size_t)NMON * NPIX;     // [2][MPAD], rows CP-padded

    float* out = (float*)d_out;

    prep_kernel<<<dim3(36 + 288), dim3(256), 0, stream>>>(
        img, net_w, net_b, u_pm, s_pm, s_cm, phi, M);
    for (int it = 0; it < NITER; it++) {
        float* Mc = M + (it & 1) * MPAD;
        float* Mn = M + ((it + 1) & 1) * MPAD;
        k1_kernel<<<dim3(NMG * 36 + NCH * 36), dim3(256), 0, stream>>>(
            s_pm, s_cm, phi, sx, Mc);
        k2_kernel<<<dim3(NPIX / K2PX), dim3(256), 0, stream>>>(
            sx, phi, Mc, Mn, u_pm, sp_w, sp_b, bl_w, bl_b, comp_w, comp_b,
            s_pm, s_cm, out, it == NITER - 1 ? 1 : 0);
    }
}

// Round 13
// 200.971 us; speedup vs baseline: 1.2495x; 1.0160x over previous
//
#include <hip/hip_runtime.h>

#define NPIX 9216
#define IMH 96
#define IMW 96
#define NC 21
#define NCH 22          // 21 classes + norm channel
#define CP 24           // pixel-major channel pad; also M row pad
#define NMON 126        // monomials of degree <=4 in 5 vars
#define PHP 128         // pixel-major phi row pitch
#define RAD 15
#define NITER 5
#define MG 11           // monomials per stage1 block
#define NMG 12          // ceil(126/11)
#define LDSS 260        // stage1 LDS pitch (float4-aligned, bank-spread)
#define MPAD 3072       // M buffer stride (>=126*24, float4-aligned)
#define K2PX 8          // k2 pixels per block (1152 blocks = 4.5/CU)

// spatial taps exp(-d^2/18), sigma=3
__constant__ float GW[16] = {
    1.0f, 0.945959f, 0.800737f, 0.606531f, 0.411112f, 0.249352f,
    0.135335f, 0.0657285f, 0.0285655f, 0.0111090f, 0.00386592f,
    0.00120386f, 0.000335463f, 8.36523e-05f, 1.86640e-05f, 3.72665e-06f};

// near-minimax deg-4 poly for exp(t) on [0, 1.0384] (all coeffs > 0)
__constant__ float d_bk[5] = {1.000000f, 0.998959f, 0.509936f, 0.139441f, 0.070024f};

// ---- P: two block roles, one dispatch. Role B writes BOTH phi layouts:
//      m-major [126][NPIX] for k1 (coalesced float4 staging) and pixel-major
//      [NPIX][128] for k2 (contiguous per-block slab). Thread's 16-monomial
//      window is consecutive in m => pixel-major writes fill whole lines. ----
__global__ __launch_bounds__(256) void prep_kernel(
    const float* __restrict__ img, const float* __restrict__ net_w,
    const float* __restrict__ net_b,
    float* __restrict__ u_pm, float* __restrict__ s_pm, float* __restrict__ s_cm,
    float* __restrict__ phi, float* __restrict__ phi_p, float* __restrict__ M0)
{
    __shared__ float wsh[567], bsh[21];
    __shared__ float sg_sh[NMON];
    const int tid = threadIdx.x;
    const int bid = blockIdx.x;

    if (bid < 36) {
        // ---- role A: unary conv + softmax + u/s + zero M0 ----
        for (int i2 = tid; i2 < 567; i2 += 256) wsh[i2] = net_w[i2];
        if (tid < 21) bsh[tid] = net_b[tid];
        __syncthreads();

        const int px = bid * 256 + tid;
        const int i = px / IMW, j = px % IMW;
        if (px < MPAD) M0[px] = 0.f;      // zero padded M buffer 0

        float acc[NC];
        #pragma unroll
        for (int o = 0; o < NC; o++) acc[o] = bsh[o];
        for (int ci = 0; ci < 3; ci++)
            for (int ky = 0; ky < 3; ky++)
                for (int kx = 0; kx < 3; kx++) {
                    const int ii = i + ky - 1, jj = j + kx - 1;
                    float v = 0.f;
                    if (ii >= 0 && ii < IMH && jj >= 0 && jj < IMW)
                        v = img[(ci * IMH + ii) * IMW + jj];
                    #pragma unroll
                    for (int o = 0; o < NC; o++)
                        acc[o] = fmaf(v, wsh[(ci * 3 + ky) * 3 + kx + o * 27], acc[o]);
                }
        {   // u then softmax
            float4* up = (float4*)(u_pm + (size_t)px * CP);
            up[0] = make_float4(acc[0], acc[1], acc[2], acc[3]);
            up[1] = make_float4(acc[4], acc[5], acc[6], acc[7]);
            up[2] = make_float4(acc[8], acc[9], acc[10], acc[11]);
            up[3] = make_float4(acc[12], acc[13], acc[14], acc[15]);
            up[4] = make_float4(acc[16], acc[17], acc[18], acc[19]);
            up[5] = make_float4(acc[20], 0.f, 0.f, 0.f);
        }
        float mx = acc[0];
        #pragma unroll
        for (int o = 1; o < NC; o++) mx = fmaxf(mx, acc[o]);
        float sum = 0.f;
        #pragma unroll
        for (int o = 0; o < NC; o++) { acc[o] = __expf(acc[o] - mx); sum += acc[o]; }
        const float inv = 1.f / sum;
        #pragma unroll
        for (int o = 0; o < NC; o++) acc[o] *= inv;
        {
            float4* sp = (float4*)(s_pm + (size_t)px * CP);
            sp[0] = make_float4(acc[0], acc[1], acc[2], acc[3]);
            sp[1] = make_float4(acc[4], acc[5], acc[6], acc[7]);
            sp[2] = make_float4(acc[8], acc[9], acc[10], acc[11]);
            sp[3] = make_float4(acc[12], acc[13], acc[14], acc[15]);
            sp[4] = make_float4(acc[16], acc[17], acc[18], acc[19]);
            sp[5] = make_float4(acc[20], 1.f, 0.f, 0.f);
        }
        #pragma unroll
        for (int o = 0; o < NC; o++) s_cm[(size_t)o * NPIX + px] = acc[o];
        s_cm[(size_t)21 * NPIX + px] = 1.f;
    } else {
        // ---- role B: phi, 8 threads/pixel, 16-monomial store window each ----
        for (int m = tid; m < NMON; m += 256) {
            int e1 = 0, e2 = 0, e3 = 0, e4 = 0, e5 = 0, cnt = 0;
            bool done = false;
            for (int a = 0; a <= 4 && !done; a++)
                for (int b2 = 0; b2 <= 4 - a && !done; b2++)
                    for (int c = 0; c <= 4 - a - b2 && !done; c++)
                        for (int d = 0; d <= 4 - a - b2 - c && !done; d++) {
                            const int rem = 4 - a - b2 - c - d;
                            if (m - cnt <= rem) {
                                e1 = a; e2 = b2; e3 = c; e4 = d; e5 = m - cnt;
                                done = true;
                            } else cnt += rem + 1;
                        }
            const float fact[5] = {1.f, 1.f, 2.f, 6.f, 24.f};
            const int k = e1 + e2 + e3 + e4 + e5;
            sg_sh[m] = sqrtf(d_bk[k] * fact[k] /
                             (fact[e1] * fact[e2] * fact[e3] * fact[e4] * fact[e5]));
        }
        __syncthreads();

        const int px = (bid - 36) * 32 + (tid & 31);
        const unsigned c0 = (tid >> 5) * 16;      // this thread's store window
        const int i = px / IMW, j = px % IMW;
        const float fv[5] = {(float)j * (1.0f / 160.0f), (float)i * (1.0f / 160.0f),
                             img[0 * NPIX + px] * (1.0f / 3.0f),
                             img[1 * NPIX + px] * (1.0f / 3.0f),
                             img[2 * NPIX + px] * (1.0f / 3.0f)};
        const float env = __expf(-0.5f * (fv[0]*fv[0] + fv[1]*fv[1] + fv[2]*fv[2] +
                                          fv[3]*fv[3] + fv[4]*fv[4]));
        int m = 0;
        float p1 = env;
        #pragma unroll
        for (int e1 = 0; e1 <= 4; e1++) {
            float p2 = p1;
            #pragma unroll
            for (int e2 = 0; e2 <= 4 - e1; e2++) {
                float p3 = p2;
                #pragma unroll
                for (int e3 = 0; e3 <= 4 - e1 - e2; e3++) {
                    float p4 = p3;
                    #pragma unroll
                    for (int e4 = 0; e4 <= 4 - e1 - e2 - e3; e4++) {
                        float p5 = p4;
                        #pragma unroll
                        for (int e5 = 0; e5 <= 4 - e1 - e2 - e3 - e4; e5++) {
                            if ((unsigned)(m - c0) < 16u) {
                                const float val = sg_sh[m] * p5;
                                phi[(size_t)m * NPIX + px] = val;
                                phi_p[(size_t)px * PHP + m] = val;
                            }
                            ++m;
                            p5 *= fv[4];
                        }
                        p4 *= fv[3];
                    }
                    p3 *= fv[2];
                }
                p2 *= fv[1];
            }
            p1 *= fv[0];
        }
    }
}

// ---- K1: stage1 GEMM (LDS b128 dot, atomic M, CP-padded rows) || conv-x ----
__global__ __launch_bounds__(256) void k1_kernel(
    const float* __restrict__ s_pm, const float* __restrict__ s_cm,
    const float* __restrict__ phi, float* __restrict__ sx, float* __restrict__ M)
{
    __shared__ float smem[(NCH + MG) * LDSS];
    const int bid = blockIdx.x, tid = threadIdx.x;
    if (bid < NMG * 36) {
        const int g = bid / 36, chunk = bid % 36;
        const int m0 = g * MG;
        const int mcnt = (NMON - m0 < MG) ? (NMON - m0) : MG;
        float* s_sh = smem;
        float* p_sh = smem + NCH * LDSS;
        {
            const float4* sp = (const float4*)(s_pm + (size_t)(chunk * 256 + tid) * CP);
            #pragma unroll
            for (int v = 0; v < 6; v++) {
                const float4 t = sp[v];
                const int c = 4 * v;
                if (c < NCH)     s_sh[c * LDSS + tid] = t.x;
                if (c + 1 < NCH) s_sh[(c + 1) * LDSS + tid] = t.y;
                if (c + 2 < NCH) s_sh[(c + 2) * LDSS + tid] = t.z;
                if (c + 3 < NCH) s_sh[(c + 3) * LDSS + tid] = t.w;
            }
        }
        for (int idx = tid; idx < mcnt * 64; idx += 256) {
            const int mm = idx >> 6, p4 = idx & 63;
            const float4 t = *(const float4*)(phi + (size_t)(m0 + mm) * NPIX +
                                              chunk * 256 + p4 * 4);
            *(float4*)(p_sh + mm * LDSS + p4 * 4) = t;
        }
        __syncthreads();
        const int c = tid % NCH, msub = tid / NCH;
        if (msub < mcnt) {
            const float* sr = s_sh + c * LDSS;
            const float* pr = p_sh + msub * LDSS;
            float acc = 0.f;
            for (int p4 = 0; p4 < 64; p4++) {
                const float4 sv = *(const float4*)(sr + p4 * 4);
                const float4 pv = *(const float4*)(pr + p4 * 4);
                acc += pv.x * sv.x + pv.y * sv.y + pv.z * sv.z + pv.w * sv.w;
            }
            atomicAdd(&M[(m0 + msub) * CP + c], acc);
        }
    } else {
        const int u2 = bid - NMG * 36;        // [0, 792)
        const int ch = u2 / 36, pc = u2 % 36;
        const int n = pc * 256 + tid, j = n % IMW;
        const float* row = s_cm + (size_t)ch * NPIX + (n - j);
        float a = GW[0] * row[j];
        #pragma unroll
        for (int d = 1; d <= RAD; d++) {
            const float l = (j - d >= 0) ? row[j - d] : 0.f;
            const float r = (j + d < IMW) ? row[j + d] : 0.f;
            a = fmaf(GW[d], l + r, a);
        }
        sx[(size_t)ch * NPIX + n] = a;
    }
}

// ---- K2: conv-y + stage2 + combine + softmax. 8 px/block, 1152 blocks.
//      phi from PIXEL-MAJOR copy: one contiguous 4 KB slab per block staged
//      into LDS [8][132] (conflict-free: bank = (4p+mm)%32 distinct). ----
__global__ __launch_bounds__(256) void k2_kernel(
    const float* __restrict__ sx, const float* __restrict__ phi_p,
    const float* __restrict__ M, float* __restrict__ Mnext,
    const float* __restrict__ u_pm,
    const float* __restrict__ sp_w, const float* __restrict__ sp_b,
    const float* __restrict__ bl_w, const float* __restrict__ bl_b,
    const float* __restrict__ comp_w, const float* __restrict__ comp_b,
    float* __restrict__ s_pm, float* __restrict__ s_cm,
    float* __restrict__ out, int write_out)
{
    __shared__ float Msh[NMON * CP];       // 12.1 KB, [126][24]
    __shared__ float phi_sh[K2PX * 132];   // 4.2 KB, pitch 132 (bank-spread)
    __shared__ float cy_sh[K2PX * 25];     // conv-y (+norm slot)
    __shared__ float blv_sh[K2PX * 25];    // stage2 result
    __shared__ float mp_sh[K2PX * CP];
    __shared__ float q_sh[K2PX * CP];      // u (prefetch) -> q
    __shared__ float wsh[1386 + 63];
    const int tid = threadIdx.x;
    const int px0 = blockIdx.x * K2PX;
    const int i0 = px0 / IMW;              // block-uniform row (8 | 96)

    // Msh: vectorized copy of padded M (pad cols are zero-initialized, unwritten)
    {
        float4* M4 = (float4*)Msh;
        const float4* Mc4 = (const float4*)M;
        for (int idx = tid; idx < NMON * CP / 4; idx += 256) M4[idx] = Mc4[idx];
    }
    // phi tile: contiguous 4 KB slab (8 px x 128), fully coalesced float4
    {
        const float4 v = *(const float4*)(phi_p + (size_t)px0 * PHP + tid * 4);
        const int row = tid >> 5, q4 = (tid & 31) * 4;
        *(float4*)(phi_sh + row * 132 + q4) = v;   // pad cols never read
    }
    for (int idx = tid; idx < 441; idx += 256) {
        wsh[idx] = sp_w[idx]; wsh[441 + idx] = bl_w[idx]; wsh[882 + idx] = comp_w[idx];
    }
    if (tid < 21) {
        wsh[1323 + tid] = sp_b[tid]; wsh[1344 + tid] = bl_b[tid];
        wsh[1365 + tid] = comp_b[tid];
    }
    if (blockIdx.x < 12) {
        const int idx = blockIdx.x * 256 + tid;
        if (idx < MPAD) Mnext[idx] = 0.f;
    }
    // u prefetch (contiguous 8*24 floats)
    for (int idx = tid; idx < K2PX * CP; idx += 256)
        q_sh[idx] = u_pm[(size_t)px0 * CP + idx];
    // conv-y: 22ch x 8px tasks (single round)
    if (tid < NCH * K2PX) {
        const int ch = tid >> 3, p = tid & 7;
        const int n = px0 + p;
        const float* plane = sx + (size_t)ch * NPIX;
        float a = GW[0] * plane[n];
        #pragma unroll
        for (int d = 1; d <= RAD; d++) {
            const float t = (i0 - d >= 0) ? plane[n - d * IMW] : 0.f;
            const float b = (i0 + d < IMH) ? plane[n + d * IMW] : 0.f;
            a = fmaf(GW[d], t + b, a);
        }
        cy_sh[p * 25 + ch] = a;
    }
    __syncthreads();

    // stage2: thread = (p = tid&7, ch = tid>>3); phi from LDS (conflict-free)
    {
        const int p = tid & 7, ch = tid >> 3;
        if (ch < NCH) {
            float a0 = 0.f;
            const float* prow = phi_sh + p * 132;
            for (int mm = 0; mm < NMON; mm++)
                a0 = fmaf(prow[mm], Msh[mm * CP + ch], a0);
            blv_sh[p * 25 + ch] = a0;
        }
    }
    __syncthreads();

    // matmul1: mp = sp_b + bl_b + (sp_w@cy)/cy_norm + (bl_w@blv)/blv_norm
    if (tid < K2PX * NC) {
        const int p = tid & 7, o = tid >> 3;
        const float* cyr = cy_sh + p * 25;
        const float* blr = blv_sh + p * 25;
        float dS = 0.f, dB = 0.f;
        #pragma unroll
        for (int c = 0; c < NC; c++) {
            dS = fmaf(wsh[o * NC + c], cyr[c], dS);
            dB = fmaf(wsh[441 + o * NC + c], blr[c], dB);
        }
        mp_sh[p * CP + o] = wsh[1323 + o] + wsh[1344 + o] +
                            dS / cyr[21] + dB / blr[21];
    }
    __syncthreads();

    // matmul2: q = u - (comp_w @ mp + comp_b)   (u already in q_sh)
    if (tid < K2PX * NC) {
        const int p = tid & 7, o = tid >> 3;
        const float* mpr = mp_sh + p * CP;
        float d = wsh[1365 + o];
        #pragma unroll
        for (int c = 0; c < NC; c++) d = fmaf(wsh[882 + o * NC + c], mpr[c], d);
        q_sh[p * CP + o] = q_sh[p * CP + o] - d;
    }
    __syncthreads();

    // softmax + writes, thread = pixel
    if (tid < K2PX) {
        const int n = px0 + tid;
        float q[NC];
        #pragma unroll
        for (int o = 0; o < NC; o++) q[o] = q_sh[tid * CP + o];
        float mx = q[0];
        #pragma unroll
        for (int o = 1; o < NC; o++) mx = fmaxf(mx, q[o]);
        float sum = 0.f;
        #pragma unroll
        for (int o = 0; o < NC; o++) { q[o] = __expf(q[o] - mx); sum += q[o]; }
        const float inv = 1.f / sum;
        #pragma unroll
        for (int o = 0; o < NC; o++) q[o] *= inv;

        float4* sp = (float4*)(s_pm + (size_t)n * CP);
        sp[0] = make_float4(q[0], q[1], q[2], q[3]);
        sp[1] = make_float4(q[4], q[5], q[6], q[7]);
        sp[2] = make_float4(q[8], q[9], q[10], q[11]);
        sp[3] = make_float4(q[12], q[13], q[14], q[15]);
        sp[4] = make_float4(q[16], q[17], q[18], q[19]);
        sp[5] = make_float4(q[20], 1.f, 0.f, 0.f);
        #pragma unroll
        for (int o = 0; o < NC; o++) s_cm[(size_t)o * NPIX + n] = q[o];
        s_cm[(size_t)21 * NPIX + n] = 1.f;
        if (write_out)
            #pragma unroll
            for (int o = 0; o < NC; o++) out[(size_t)o * NPIX + n] = q[o];
    }
}

extern "C" void kernel_launch(void* const* d_in, const int* in_sizes, int n_in,
                              void* d_out, int out_size, void* d_ws, size_t ws_size,
                              hipStream_t stream) {
    const float* img    = (const float*)d_in[0];
    const float* net_w  = (const float*)d_in[1];
    const float* net_b  = (const float*)d_in[2];
    const float* sp_w   = (const float*)d_in[3];
    const float* sp_b   = (const float*)d_in[4];
    const float* bl_w   = (const float*)d_in[5];
    const float* bl_b   = (const float*)d_in[6];
    const float* comp_w = (const float*)d_in[7];
    const float* comp_b = (const float*)d_in[8];

    float* u_pm  = (float*)d_ws;                 // [NPIX][24]
    float* s_pm  = u_pm + (size_t)NPIX * CP;     // [NPIX][24]
    float* s_cm  = s_pm + (size_t)NPIX * CP;     // [22][NPIX]
    float* sx    = s_cm + (size_t)NCH * NPIX;    // [22][NPIX]
    float* phi   = sx + (size_t)NCH * NPIX;      // [126][NPIX] (m-major, k1)
    float* phi_p = phi + (size_t)NMON * NPIX;    // [NPIX][128] (px-major, k2)
    float* M     = phi_p + (size_t)NPIX * PHP;   // [2][MPAD], rows CP-padded

    float* out = (float*)d_out;

    prep_kernel<<<dim3(36 + 288), dim3(256), 0, stream>>>(
        img, net_w, net_b, u_pm, s_pm, s_cm, phi, phi_p, M);
    for (int it = 0; it < NITER; it++) {
        float* Mc = M + (it & 1) * MPAD;
        float* Mn = M + ((it + 1) & 1) * MPAD;
        k1_kernel<<<dim3(NMG * 36 + NCH * 36), dim3(256), 0, stream>>>(
            s_pm, s_cm, phi, sx, Mc);
        k2_kernel<<<dim3(NPIX / K2PX), dim3(256), 0, stream>>>(
            sx, phi_p, Mc, Mn, u_pm, sp_w, sp_b, bl_w, bl_b, comp_w, comp_b,
            s_pm, s_cm, out, it == NITER - 1 ? 1 : 0);
    }
}

// Round 14
// 200.551 us; speedup vs baseline: 1.2521x; 1.0021x over previous
//
#include <hip/hip_runtime.h>

#define NPIX 9216
#define IMH 96
#define IMW 96
#define NC 21
#define NCH 22          // 21 classes + norm channel
#define CP 24           // pixel-major channel pad; also M row pad
#define NMON 126        // monomials of degree <=4 in 5 vars
#define PHP 128         // pixel-major phi row pitch
#define RAD 15
#define NITER 5
#define MG 11           // monomials per stage1 block
#define NMG 12          // ceil(126/11)
#define LDSS 260        // stage1 LDS pitch (float4-aligned, bank-spread)
#define MPAD 3072       // M buffer stride (>=126*24, float4-aligned)
#define K2PX 8          // k2 pixels per block (1152 blocks = 4.5/CU)
#define K1G (NMG * 36 + NCH * 36)   // 1224 base k1 blocks
#define TRB 144         // transpose blocks (it=0 only), 64 px each

// spatial taps exp(-d^2/18), sigma=3
__constant__ float GW[16] = {
    1.0f, 0.945959f, 0.800737f, 0.606531f, 0.411112f, 0.249352f,
    0.135335f, 0.0657285f, 0.0285655f, 0.0111090f, 0.00386592f,
    0.00120386f, 0.000335463f, 8.36523e-05f, 1.86640e-05f, 3.72665e-06f};

// near-minimax deg-4 poly for exp(t) on [0, 1.0384] (all coeffs > 0)
__constant__ float d_bk[5] = {1.000000f, 0.998959f, 0.509936f, 0.139441f, 0.070024f};

// ---- P: two block roles, one dispatch (round-12 form: m-major phi only) ----
__global__ __launch_bounds__(256) void prep_kernel(
    const float* __restrict__ img, const float* __restrict__ net_w,
    const float* __restrict__ net_b,
    float* __restrict__ u_pm, float* __restrict__ s_pm, float* __restrict__ s_cm,
    float* __restrict__ phi, float* __restrict__ M0)
{
    __shared__ float wsh[567], bsh[21];
    __shared__ float sg_sh[NMON];
    const int tid = threadIdx.x;
    const int bid = blockIdx.x;

    if (bid < 36) {
        // ---- role A: unary conv + softmax + u/s + zero M0 ----
        for (int i2 = tid; i2 < 567; i2 += 256) wsh[i2] = net_w[i2];
        if (tid < 21) bsh[tid] = net_b[tid];
        __syncthreads();

        const int px = bid * 256 + tid;
        const int i = px / IMW, j = px % IMW;
        if (px < MPAD) M0[px] = 0.f;      // zero padded M buffer 0

        float acc[NC];
        #pragma unroll
        for (int o = 0; o < NC; o++) acc[o] = bsh[o];
        for (int ci = 0; ci < 3; ci++)
            for (int ky = 0; ky < 3; ky++)
                for (int kx = 0; kx < 3; kx++) {
                    const int ii = i + ky - 1, jj = j + kx - 1;
                    float v = 0.f;
                    if (ii >= 0 && ii < IMH && jj >= 0 && jj < IMW)
                        v = img[(ci * IMH + ii) * IMW + jj];
                    #pragma unroll
                    for (int o = 0; o < NC; o++)
                        acc[o] = fmaf(v, wsh[(ci * 3 + ky) * 3 + kx + o * 27], acc[o]);
                }
        {   // u then softmax
            float4* up = (float4*)(u_pm + (size_t)px * CP);
            up[0] = make_float4(acc[0], acc[1], acc[2], acc[3]);
            up[1] = make_float4(acc[4], acc[5], acc[6], acc[7]);
            up[2] = make_float4(acc[8], acc[9], acc[10], acc[11]);
            up[3] = make_float4(acc[12], acc[13], acc[14], acc[15]);
            up[4] = make_float4(acc[16], acc[17], acc[18], acc[19]);
            up[5] = make_float4(acc[20], 0.f, 0.f, 0.f);
        }
        float mx = acc[0];
        #pragma unroll
        for (int o = 1; o < NC; o++) mx = fmaxf(mx, acc[o]);
        float sum = 0.f;
        #pragma unroll
        for (int o = 0; o < NC; o++) { acc[o] = __expf(acc[o] - mx); sum += acc[o]; }
        const float inv = 1.f / sum;
        #pragma unroll
        for (int o = 0; o < NC; o++) acc[o] *= inv;
        {
            float4* sp = (float4*)(s_pm + (size_t)px * CP);
            sp[0] = make_float4(acc[0], acc[1], acc[2], acc[3]);
            sp[1] = make_float4(acc[4], acc[5], acc[6], acc[7]);
            sp[2] = make_float4(acc[8], acc[9], acc[10], acc[11]);
            sp[3] = make_float4(acc[12], acc[13], acc[14], acc[15]);
            sp[4] = make_float4(acc[16], acc[17], acc[18], acc[19]);
            sp[5] = make_float4(acc[20], 1.f, 0.f, 0.f);
        }
        #pragma unroll
        for (int o = 0; o < NC; o++) s_cm[(size_t)o * NPIX + px] = acc[o];
        s_cm[(size_t)21 * NPIX + px] = 1.f;
    } else {
        // ---- role B: phi (m-major only), 8 threads/pixel ----
        for (int m = tid; m < NMON; m += 256) {
            int e1 = 0, e2 = 0, e3 = 0, e4 = 0, e5 = 0, cnt = 0;
            bool done = false;
            for (int a = 0; a <= 4 && !done; a++)
                for (int b2 = 0; b2 <= 4 - a && !done; b2++)
                    for (int c = 0; c <= 4 - a - b2 && !done; c++)
                        for (int d = 0; d <= 4 - a - b2 - c && !done; d++) {
                            const int rem = 4 - a - b2 - c - d;
                            if (m - cnt <= rem) {
                                e1 = a; e2 = b2; e3 = c; e4 = d; e5 = m - cnt;
                                done = true;
                            } else cnt += rem + 1;
                        }
            const float fact[5] = {1.f, 1.f, 2.f, 6.f, 24.f};
            const int k = e1 + e2 + e3 + e4 + e5;
            sg_sh[m] = sqrtf(d_bk[k] * fact[k] /
                             (fact[e1] * fact[e2] * fact[e3] * fact[e4] * fact[e5]));
        }
        __syncthreads();

        const int px = (bid - 36) * 32 + (tid & 31);
        const unsigned c0 = (tid >> 5) * 16;      // this thread's store window
        const int i = px / IMW, j = px % IMW;
        const float fv[5] = {(float)j * (1.0f / 160.0f), (float)i * (1.0f / 160.0f),
                             img[0 * NPIX + px] * (1.0f / 3.0f),
                             img[1 * NPIX + px] * (1.0f / 3.0f),
                             img[2 * NPIX + px] * (1.0f / 3.0f)};
        const float env = __expf(-0.5f * (fv[0]*fv[0] + fv[1]*fv[1] + fv[2]*fv[2] +
                                          fv[3]*fv[3] + fv[4]*fv[4]));
        int m = 0;
        float p1 = env;
        #pragma unroll
        for (int e1 = 0; e1 <= 4; e1++) {
            float p2 = p1;
            #pragma unroll
            for (int e2 = 0; e2 <= 4 - e1; e2++) {
                float p3 = p2;
                #pragma unroll
                for (int e3 = 0; e3 <= 4 - e1 - e2; e3++) {
                    float p4 = p3;
                    #pragma unroll
                    for (int e4 = 0; e4 <= 4 - e1 - e2 - e3; e4++) {
                        float p5 = p4;
                        #pragma unroll
                        for (int e5 = 0; e5 <= 4 - e1 - e2 - e3 - e4; e5++) {
                            if ((unsigned)(m - c0) < 16u)
                                phi[(size_t)m * NPIX + px] = sg_sh[m] * p5;
                            ++m;
                            p5 *= fv[4];
                        }
                        p4 *= fv[3];
                    }
                    p3 *= fv[2];
                }
                p2 *= fv[1];
            }
            p1 *= fv[0];
        }
    }
}

// ---- K1: stage1 GEMM || conv-x || (it=0 only) phi transpose to pixel-major ----
__global__ __launch_bounds__(256) void k1_kernel(
    const float* __restrict__ s_pm, const float* __restrict__ s_cm,
    const float* __restrict__ phi, float* __restrict__ phi_p,
    float* __restrict__ sx, float* __restrict__ M)
{
    __shared__ float smem[(NCH + MG) * LDSS];    // 34.3 KB (transpose needs 33.8)
    const int bid = blockIdx.x, tid = threadIdx.x;
    if (bid < NMG * 36) {
        const int g = bid / 36, chunk = bid % 36;
        const int m0 = g * MG;
        const int mcnt = (NMON - m0 < MG) ? (NMON - m0) : MG;
        float* s_sh = smem;
        float* p_sh = smem + NCH * LDSS;
        {
            const float4* sp = (const float4*)(s_pm + (size_t)(chunk * 256 + tid) * CP);
            #pragma unroll
            for (int v = 0; v < 6; v++) {
                const float4 t = sp[v];
                const int c = 4 * v;
                if (c < NCH)     s_sh[c * LDSS + tid] = t.x;
                if (c + 1 < NCH) s_sh[(c + 1) * LDSS + tid] = t.y;
                if (c + 2 < NCH) s_sh[(c + 2) * LDSS + tid] = t.z;
                if (c + 3 < NCH) s_sh[(c + 3) * LDSS + tid] = t.w;
            }
        }
        for (int idx = tid; idx < mcnt * 64; idx += 256) {
            const int mm = idx >> 6, p4 = idx & 63;
            const float4 t = *(const float4*)(phi + (size_t)(m0 + mm) * NPIX +
                                              chunk * 256 + p4 * 4);
            *(float4*)(p_sh + mm * LDSS + p4 * 4) = t;
        }
        __syncthreads();
        const int c = tid % NCH, msub = tid / NCH;
        if (msub < mcnt) {
            const float* sr = s_sh + c * LDSS;
            const float* pr = p_sh + msub * LDSS;
            float acc = 0.f;
            for (int p4 = 0; p4 < 64; p4++) {
                const float4 sv = *(const float4*)(sr + p4 * 4);
                const float4 pv = *(const float4*)(pr + p4 * 4);
                acc += pv.x * sv.x + pv.y * sv.y + pv.z * sv.z + pv.w * sv.w;
            }
            atomicAdd(&M[(m0 + msub) * CP + c], acc);
        }
    } else if (bid < K1G) {
        const int u2 = bid - NMG * 36;        // [0, 792)
        const int ch = u2 / 36, pc = u2 % 36;
        const int n = pc * 256 + tid, j = n % IMW;
        const float* row = s_cm + (size_t)ch * NPIX + (n - j);
        float a = GW[0] * row[j];
        #pragma unroll
        for (int d = 1; d <= RAD; d++) {
            const float l = (j - d >= 0) ? row[j - d] : 0.f;
            const float r = (j + d < IMW) ? row[j + d] : 0.f;
            a = fmaf(GW[d], l + r, a);
        }
        sx[(size_t)ch * NPIX + n] = a;
    } else {
        // ---- transpose role (it=0 only): phi [126][NPIX] -> phi_p [NPIX][128]
        //      64 px per block; coalesced read, LDS [64][132], coalesced write.
        const int t = bid - K1G;              // [0,144)
        const int px0 = t * 64;
        float* lds = smem;
        for (int idx = tid; idx < NMON * 16; idx += 256) {
            const int m = idx >> 4, q = idx & 15;
            const float4 v = *(const float4*)(phi + (size_t)m * NPIX + px0 + q * 4);
            lds[(q * 4 + 0) * 132 + m] = v.x;
            lds[(q * 4 + 1) * 132 + m] = v.y;
            lds[(q * 4 + 2) * 132 + m] = v.z;
            lds[(q * 4 + 3) * 132 + m] = v.w;
        }
        __syncthreads();
        for (int idx = tid; idx < 64 * 32; idx += 256) {
            const int px = idx >> 5, q = idx & 31;
            const int m0 = q * 4;
            float4 v;
            v.x = (m0 + 0 < NMON) ? lds[px * 132 + m0 + 0] : 0.f;
            v.y = (m0 + 1 < NMON) ? lds[px * 132 + m0 + 1] : 0.f;
            v.z = (m0 + 2 < NMON) ? lds[px * 132 + m0 + 2] : 0.f;
            v.w = (m0 + 3 < NMON) ? lds[px * 132 + m0 + 3] : 0.f;
            *(float4*)(phi_p + (size_t)(px0 + px) * PHP + m0) = v;
        }
    }
}

// ---- K2: conv-y + stage2 + combine + softmax. 8 px/block, 1152 blocks.
//      phi from PIXEL-MAJOR copy: one contiguous 4 KB slab per block staged
//      into LDS [8][132] (conflict-free). ----
__global__ __launch_bounds__(256) void k2_kernel(
    const float* __restrict__ sx, const float* __restrict__ phi_p,
    const float* __restrict__ M, float* __restrict__ Mnext,
    const float* __restrict__ u_pm,
    const float* __restrict__ sp_w, const float* __restrict__ sp_b,
    const float* __restrict__ bl_w, const float* __restrict__ bl_b,
    const float* __restrict__ comp_w, const float* __restrict__ comp_b,
    float* __restrict__ s_pm, float* __restrict__ s_cm,
    float* __restrict__ out, int write_out)
{
    __shared__ float Msh[NMON * CP];       // 12.1 KB, [126][24]
    __shared__ float phi_sh[K2PX * 132];   // 4.2 KB, pitch 132 (bank-spread)
    __shared__ float cy_sh[K2PX * 25];     // conv-y (+norm slot)
    __shared__ float blv_sh[K2PX * 25];    // stage2 result
    __shared__ float mp_sh[K2PX * CP];
    __shared__ float q_sh[K2PX * CP];      // u (prefetch) -> q
    __shared__ float wsh[1386 + 63];
    const int tid = threadIdx.x;
    const int px0 = blockIdx.x * K2PX;
    const int i0 = px0 / IMW;              // block-uniform row (8 | 96)

    // Msh: vectorized copy of padded M (pad cols are zero-initialized, unwritten)
    {
        float4* M4 = (float4*)Msh;
        const float4* Mc4 = (const float4*)M;
        for (int idx = tid; idx < NMON * CP / 4; idx += 256) M4[idx] = Mc4[idx];
    }
    // phi tile: contiguous 4 KB slab (8 px x 128), fully coalesced float4
    {
        const float4 v = *(const float4*)(phi_p + (size_t)px0 * PHP + tid * 4);
        const int row = tid >> 5, q4 = (tid & 31) * 4;
        *(float4*)(phi_sh + row * 132 + q4) = v;   // pad cols never read
    }
    for (int idx = tid; idx < 441; idx += 256) {
        wsh[idx] = sp_w[idx]; wsh[441 + idx] = bl_w[idx]; wsh[882 + idx] = comp_w[idx];
    }
    if (tid < 21) {
        wsh[1323 + tid] = sp_b[tid]; wsh[1344 + tid] = bl_b[tid];
        wsh[1365 + tid] = comp_b[tid];
    }
    if (blockIdx.x < 12) {
        const int idx = blockIdx.x * 256 + tid;
        if (idx < MPAD) Mnext[idx] = 0.f;
    }
    // u prefetch (contiguous 8*24 floats)
    for (int idx = tid; idx < K2PX * CP; idx += 256)
        q_sh[idx] = u_pm[(size_t)px0 * CP + idx];
    // conv-y: 22ch x 8px tasks (single round)
    if (tid < NCH * K2PX) {
        const int ch = tid >> 3, p = tid & 7;
        const int n = px0 + p;
        const float* plane = sx + (size_t)ch * NPIX;
        float a = GW[0] * plane[n];
        #pragma unroll
        for (int d = 1; d <= RAD; d++) {
            const float t = (i0 - d >= 0) ? plane[n - d * IMW] : 0.f;
            const float b = (i0 + d < IMH) ? plane[n + d * IMW] : 0.f;
            a = fmaf(GW[d], t + b, a);
        }
        cy_sh[p * 25 + ch] = a;
    }
    __syncthreads();

    // stage2: thread = (p = tid&7, ch = tid>>3); phi from LDS (conflict-free)
    {
        const int p = tid & 7, ch = tid >> 3;
        if (ch < NCH) {
            float a0 = 0.f;
            const float* prow = phi_sh + p * 132;
            for (int mm = 0; mm < NMON; mm++)
                a0 = fmaf(prow[mm], Msh[mm * CP + ch], a0);
            blv_sh[p * 25 + ch] = a0;
        }
    }
    __syncthreads();

    // matmul1: mp = sp_b + bl_b + (sp_w@cy)/cy_norm + (bl_w@blv)/blv_norm
    if (tid < K2PX * NC) {
        const int p = tid & 7, o = tid >> 3;
        const float* cyr = cy_sh + p * 25;
        const float* blr = blv_sh + p * 25;
        float dS = 0.f, dB = 0.f;
        #pragma unroll
        for (int c = 0; c < NC; c++) {
            dS = fmaf(wsh[o * NC + c], cyr[c], dS);
            dB = fmaf(wsh[441 + o * NC + c], blr[c], dB);
        }
        mp_sh[p * CP + o] = wsh[1323 + o] + wsh[1344 + o] +
                            dS / cyr[21] + dB / blr[21];
    }
    __syncthreads();

    // matmul2: q = u - (comp_w @ mp + comp_b)   (u already in q_sh)
    if (tid < K2PX * NC) {
        const int p = tid & 7, o = tid >> 3;
        const float* mpr = mp_sh + p * CP;
        float d = wsh[1365 + o];
        #pragma unroll
        for (int c = 0; c < NC; c++) d = fmaf(wsh[882 + o * NC + c], mpr[c], d);
        q_sh[p * CP + o] = q_sh[p * CP + o] - d;
    }
    __syncthreads();

    // softmax + writes, thread = pixel
    if (tid < K2PX) {
        const int n = px0 + tid;
        float q[NC];
        #pragma unroll
        for (int o = 0; o < NC; o++) q[o] = q_sh[tid * CP + o];
        float mx = q[0];
        #pragma unroll
        for (int o = 1; o < NC; o++) mx = fmaxf(mx, q[o]);
        float sum = 0.f;
        #pragma unroll
        for (int o = 0; o < NC; o++) { q[o] = __expf(q[o] - mx); sum += q[o]; }
        const float inv = 1.f / sum;
        #pragma unroll
        for (int o = 0; o < NC; o++) q[o] *= inv;

        float4* sp = (float4*)(s_pm + (size_t)n * CP);
        sp[0] = make_float4(q[0], q[1], q[2], q[3]);
        sp[1] = make_float4(q[4], q[5], q[6], q[7]);
        sp[2] = make_float4(q[8], q[9], q[10], q[11]);
        sp[3] = make_float4(q[12], q[13], q[14], q[15]);
        sp[4] = make_float4(q[16], q[17], q[18], q[19]);
        sp[5] = make_float4(q[20], 1.f, 0.f, 0.f);
        #pragma unroll
        for (int o = 0; o < NC; o++) s_cm[(size_t)o * NPIX + n] = q[o];
        s_cm[(size_t)21 * NPIX + n] = 1.f;
        if (write_out)
            #pragma unroll
            for (int o = 0; o < NC; o++) out[(size_t)o * NPIX + n] = q[o];
    }
}

extern "C" void kernel_launch(void* const* d_in, const int* in_sizes, int n_in,
                              void* d_out, int out_size, void* d_ws, size_t ws_size,
                              hipStream_t stream) {
    const float* img    = (const float*)d_in[0];
    const float* net_w  = (const float*)d_in[1];
    const float* net_b  = (const float*)d_in[2];
    const float* sp_w   = (const float*)d_in[3];
    const float* sp_b   = (const float*)d_in[4];
    const float* bl_w   = (const float*)d_in[5];
    const float* bl_b   = (const float*)d_in[6];
    const float* comp_w = (const float*)d_in[7];
    const float* comp_b = (const float*)d_in[8];

    float* u_pm  = (float*)d_ws;                 // [NPIX][24]
    float* s_pm  = u_pm + (size_t)NPIX * CP;     // [NPIX][24]
    float* s_cm  = s_pm + (size_t)NPIX * CP;     // [22][NPIX]
    float* sx    = s_cm + (size_t)NCH * NPIX;    // [22][NPIX]
    float* phi   = sx + (size_t)NCH * NPIX;      // [126][NPIX] (m-major, k1)
    float* phi_p = phi + (size_t)NMON * NPIX;    // [NPIX][128] (px-major, k2)
    float* M     = phi_p + (size_t)NPIX * PHP;   // [2][MPAD], rows CP-padded

    float* out = (float*)d_out;

    prep_kernel<<<dim3(36 + 288), dim3(256), 0, stream>>>(
        img, net_w, net_b, u_pm, s_pm, s_cm, phi, M);
    for (int it = 0; it < NITER; it++) {
        float* Mc = M + (it & 1) * MPAD;
        float* Mn = M + ((it + 1) & 1) * MPAD;
        k1_kernel<<<dim3(K1G + (it == 0 ? TRB : 0)), dim3(256), 0, stream>>>(
            s_pm, s_cm, phi, phi_p, sx, Mc);
        k2_kernel<<<dim3(NPIX / K2PX), dim3(256), 0, stream>>>(
            sx, phi_p, Mc, Mn, u_pm, sp_w, sp_b, bl_w, bl_b, comp_w, comp_b,
            s_pm, s_cm, out, it == NITER - 1 ? 1 : 0);
    }
}